// Round 12
// baseline (854.485 us; speedup 1.0000x reference)
//
#include <hip/hip_runtime.h>

// ---------------------------------------------------------------------------
// PaiNN edge message kernel, MI355X (gfx950)
// E=262144, F=128. Split-bf16 (hi/lo) MFMA GEMMs, fp32 elsewhere.
// R11/R12: 32-edge tiles (was 16). R10 showed 2 waves/SIMD is the occupancy
// ceiling (unified arch+AGPR file: 256 regs/wave at launch_bounds(512,2);
// weights need the arch half). So hide latency with per-wave ILP instead:
// 2x independent MFMA chains (hacc0/1, pacc0/1), barriers-per-edge halved,
// weight-remat amortized 2x. Keep balanced fc mapping {w,w+8,w+16},
// v-prefetch at tile top, 2 lgkmcnt-only barriers per tile.
// ---------------------------------------------------------------------------

#define E_TOT  262144
#define NTILES 8192      // E / 32
#define NBLK   512       // 16 tiles per block
#define PART_STRIDE 896  // per-block partials: v1[3][128] v2[3][128] s[128]

typedef __attribute__((ext_vector_type(8))) short bf16x8;
typedef __attribute__((ext_vector_type(4))) float f32x4;

union U8 { bf16x8 v; unsigned short u[8]; };

static __device__ __forceinline__ unsigned short f2bf(float f) {
  union { float f; unsigned u; } x; x.f = f;
  unsigned r = x.u + 0x7fffu + ((x.u >> 16) & 1u);   // RNE
  return (unsigned short)(r >> 16);
}
static __device__ __forceinline__ float bf2f(unsigned short h) {
  union { unsigned u; float f; } x; x.u = ((unsigned)h) << 16;
  return x.f;
}

// lgkmcnt-only barrier (m201 pattern): LDS-correct, global loads stay in
// flight across it (no vmcnt(0) drain).
#define BAR() do {                                           \
    asm volatile("s_waitcnt lgkmcnt(0)" ::: "memory");       \
    __builtin_amdgcn_s_barrier();                            \
    asm volatile("" ::: "memory");                           \
  } while (0)

// --- kernel 1: weights -> bf16 hi/lo pairs, transposed for B-fragments ----
__global__ void prep_kernel(const float* __restrict__ W1, const float* __restrict__ W2,
                            const float* __restrict__ Wr,
                            unsigned short* __restrict__ w1t, unsigned short* __restrict__ w2t,
                            unsigned short* __restrict__ wrt) {
  int idx = blockIdx.x * 256 + threadIdx.x;
  if (idx < 16384) {                       // W1 (128x128) -> W1T[col][k]
    int k = idx >> 7, c = idx & 127;
    float x = W1[idx];
    unsigned short hi = f2bf(x);
    w1t[c * 128 + k] = hi;
    w1t[16384 + c * 128 + k] = f2bf(x - bf2f(hi));
  } else if (idx < 65536) {                // W2 (128x384) -> W2T[col][k]
    int i = idx - 16384;
    int k = i / 384, c = i % 384;
    float x = W2[i];
    unsigned short hi = f2bf(x);
    w2t[c * 128 + k] = hi;
    w2t[49152 + c * 128 + k] = f2bf(x - bf2f(hi));
  } else if (idx < 77824) {                // Wr (20x384) -> WrT[col][n], n padded to 32
    int i = idx - 65536;
    int c = i >> 5, n = i & 31;
    float x = (n < 20) ? Wr[n * 384 + c] : 0.0f;
    unsigned short hi = f2bf(x);
    wrt[c * 32 + n] = hi;
    wrt[12288 + c * 32 + n] = f2bf(x - bf2f(hi));
  }
}

// --- kernel 2: main. 512 threads = 8 waves. Tile = 32 edges. --------------
__global__ __launch_bounds__(512, 2) void painn_main(
    const float* __restrict__ s, const float* __restrict__ r, const float* __restrict__ v,
    const float* __restrict__ b1, const float* __restrict__ b2, const float* __restrict__ br,
    const unsigned short* __restrict__ w1t, const unsigned short* __restrict__ w2t,
    const unsigned short* __restrict__ wrt, float* __restrict__ partials)
{
  __shared__ __align__(16) unsigned short sAh[32][136], sAl[32][136];
  __shared__ __align__(16) unsigned short hAh[32][136], hAl[32][136];
  __shared__ __align__(16) unsigned short rbfh[2][32][40], rbfl[2][32][40];
  __shared__ float4 urA[2][32];   // dbuf: {ux, uy, uz, fcut}

  const int tid = threadIdx.x;
  const int wv  = tid >> 6;
  const int ln  = tid & 63;
  const int l15 = ln & 15;
  const int q4  = ln >> 4;
  const int jcol = wv * 16 + l15;          // per-wave column slot, 0..127

  // zero rbf pad cols 20..31 (read by K=32 MFMA) for both buffers, hi+lo
  for (int i = tid; i < 2 * 32 * 12; i += 512) {
    const int b = i / 384, rw = (i / 12) % 32, cc = 20 + (i % 12);
    rbfh[b][rw][cc] = 0; rbfl[b][rw][cc] = 0;
  }

  // ---- weight fragments (hi/lo); allocator remats overflow from L2 ----
  bf16x8 w1fh[4], w1fl[4];
#pragma unroll
  for (int ks = 0; ks < 4; ++ks) {
    w1fh[ks] = *(const bf16x8*)(w1t + jcol * 128 + ks * 32 + q4 * 8);
    w1fl[ks] = *(const bf16x8*)(w1t + 16384 + jcol * 128 + ks * 32 + q4 * 8);
  }
  const float b1v = b1[jcol];

  float b2v[3], brv[3];
  bf16x8 w2fh[3][4], w2fl[3][4], wrfh[3], wrfl[3];
#pragma unroll
  for (int fci = 0; fci < 3; ++fci) {
    const int j = jcol + fci * 128;        // fc = wv + 8*fci
    b2v[fci] = b2[j];
    brv[fci] = br[j];
#pragma unroll
    for (int ks = 0; ks < 4; ++ks) {
      w2fh[fci][ks] = *(const bf16x8*)(w2t + j * 128 + ks * 32 + q4 * 8);
      w2fl[fci][ks] = *(const bf16x8*)(w2t + 49152 + j * 128 + ks * 32 + q4 * 8);
    }
    wrfh[fci] = *(const bf16x8*)(wrt + j * 32 + q4 * 8);
    wrfl[fci] = *(const bf16x8*)(wrt + 12288 + j * 32 + q4 * 8);
  }

  float accS = 0.f;
  float accV1[3] = {0.f, 0.f, 0.f};
  float accV2[3] = {0.f, 0.f, 0.f};
  const f32x4 zero4 = {0.f, 0.f, 0.f, 0.f};

  // ---- prefetch s (2 float4/thread) + r (every thread: its edge tid&31) --
  const int srow = tid >> 4;               // 0..31
  const int sc8  = (tid & 15) * 8;         // float col 0..120
  float4 pfa, pfb;
  {
    const float* sp = s + (size_t)((size_t)blockIdx.x * 32 + srow) * 128 + sc8;
    pfa = *(const float4*)sp;
    pfb = *(const float4*)(sp + 4);
  }
  float rx, ry, rz;
  {
    const float* rp = r + ((size_t)blockIdx.x * 32 + (tid & 31)) * 3;
    rx = rp[0]; ry = rp[1]; rz = rp[2];
  }

  int p = 0;
  for (int t = blockIdx.x; t < NTILES; t += NBLK, p ^= 1) {
    const int e0 = t * 32;

    // ---- v-prefetch for THIS tile (consumed in epilogue, ~2 phases later)
    float vp0[4][3], vp1[4][3];
    {
      const float* vb = v + (size_t)e0 * 384 + jcol;
#pragma unroll
      for (int rr = 0; rr < 4; ++rr) {
        const int el0 = q4 * 4 + rr;
#pragma unroll
        for (int c = 0; c < 3; ++c) {
          vp0[rr][c] = vb[(size_t)el0 * 384 + c * 128];
          vp1[rr][c] = vb[(size_t)(16 + el0) * 384 + c * 128];
        }
      }
    }

    // ---- phase A: stage s tile (hi/lo), geometry + rbf from local r ----
    {
      U8 vh, vl;
      unsigned short h0 = f2bf(pfa.x); vh.u[0] = h0; vl.u[0] = f2bf(pfa.x - bf2f(h0));
      unsigned short h1 = f2bf(pfa.y); vh.u[1] = h1; vl.u[1] = f2bf(pfa.y - bf2f(h1));
      unsigned short h2 = f2bf(pfa.z); vh.u[2] = h2; vl.u[2] = f2bf(pfa.z - bf2f(h2));
      unsigned short h3 = f2bf(pfa.w); vh.u[3] = h3; vl.u[3] = f2bf(pfa.w - bf2f(h3));
      unsigned short h4 = f2bf(pfb.x); vh.u[4] = h4; vl.u[4] = f2bf(pfb.x - bf2f(h4));
      unsigned short h5 = f2bf(pfb.y); vh.u[5] = h5; vl.u[5] = f2bf(pfb.y - bf2f(h5));
      unsigned short h6 = f2bf(pfb.z); vh.u[6] = h6; vl.u[6] = f2bf(pfb.z - bf2f(h6));
      unsigned short h7 = f2bf(pfb.w); vh.u[7] = h7; vl.u[7] = f2bf(pfb.w - bf2f(h7));
      *(bf16x8*)&sAh[srow][sc8] = vh.v;
      *(bf16x8*)&sAl[srow][sc8] = vl.v;
    }
    {
      const float d = sqrtf(rx * rx + ry * ry + rz * rz);
      const float inv = 1.0f / d;
      const int e_ = tid & 31;
      const int n  = tid >> 5;             // 0..15
      const float val = sinf(0.62831853071795864f * (float)(n + 1) * d) * inv;
      const unsigned short hi = f2bf(val);
      rbfh[p][e_][n] = hi;
      rbfl[p][e_][n] = f2bf(val - bf2f(hi));
      if (tid < 128) {                     // n = 16..19
        const int n2 = 16 + n;
        const float v2 = sinf(0.62831853071795864f * (float)(n2 + 1) * d) * inv;
        const unsigned short hi2 = f2bf(v2);
        rbfh[p][e_][n2] = hi2;
        rbfl[p][e_][n2] = f2bf(v2 - bf2f(hi2));
      }
      if (tid < 32) {
        const float fcut = (d < 5.0f) ? 0.5f * (cosf(0.62831853071795864f * d) + 1.0f) : 0.0f;
        float4 u4; u4.x = rx * inv; u4.y = ry * inv; u4.z = rz * inv; u4.w = fcut;
        urA[p][tid] = u4;
      }
    }
    BAR();   // sync1: sA visible

    // ---- GEMM1: h_pre = s@W1 (split, 24 MFMA, 2 independent chains) ----
    f32x4 hacc0 = zero4, hacc1 = zero4;
#pragma unroll
    for (int ks = 0; ks < 4; ++ks) {
      const bf16x8 a0h = *(const bf16x8*)&sAh[l15][ks * 32 + q4 * 8];
      const bf16x8 a0l = *(const bf16x8*)&sAl[l15][ks * 32 + q4 * 8];
      const bf16x8 a1h = *(const bf16x8*)&sAh[16 + l15][ks * 32 + q4 * 8];
      const bf16x8 a1l = *(const bf16x8*)&sAl[16 + l15][ks * 32 + q4 * 8];
      hacc0 = __builtin_amdgcn_mfma_f32_16x16x32_bf16(a0h, w1fh[ks], hacc0, 0, 0, 0);
      hacc1 = __builtin_amdgcn_mfma_f32_16x16x32_bf16(a1h, w1fh[ks], hacc1, 0, 0, 0);
      hacc0 = __builtin_amdgcn_mfma_f32_16x16x32_bf16(a0l, w1fh[ks], hacc0, 0, 0, 0);
      hacc1 = __builtin_amdgcn_mfma_f32_16x16x32_bf16(a1l, w1fh[ks], hacc1, 0, 0, 0);
      hacc0 = __builtin_amdgcn_mfma_f32_16x16x32_bf16(a0h, w1fl[ks], hacc0, 0, 0, 0);
      hacc1 = __builtin_amdgcn_mfma_f32_16x16x32_bf16(a1h, w1fl[ks], hacc1, 0, 0, 0);
    }
    // silu fp32, split-store h (D layout: row=q4*4+rr, col=jcol)
#pragma unroll
    for (int rr = 0; rr < 4; ++rr) {
      {
        const float x = hacc0[rr] + b1v;
        const float hvv = x / (1.0f + __expf(-x));
        const unsigned short hi = f2bf(hvv);
        hAh[q4 * 4 + rr][jcol] = hi;
        hAl[q4 * 4 + rr][jcol] = f2bf(hvv - bf2f(hi));
      }
      {
        const float x = hacc1[rr] + b1v;
        const float hvv = x / (1.0f + __expf(-x));
        const unsigned short hi = f2bf(hvv);
        hAh[16 + q4 * 4 + rr][jcol] = hi;
        hAl[16 + q4 * 4 + rr][jcol] = f2bf(hvv - bf2f(hi));
      }
    }

    // ---- s/r prefetch for tile t+NBLK (stays in flight across barriers) ----
    {
      int tn = t + NBLK;
      if (tn >= NTILES) tn = blockIdx.x;   // harmless valid address
      const float* sp = s + (size_t)((size_t)tn * 32 + srow) * 128 + sc8;
      pfa = *(const float4*)sp;
      pfb = *(const float4*)(sp + 4);
      const float* rp = r + ((size_t)tn * 32 + (tid & 31)) * 3;
      rx = rp[0]; ry = rp[1]; rz = rp[2];
    }
    BAR();   // sync2: hA + rbf visible

    // ---- Wfilt = rbf@Wr (K=32, split, 18 MFMA) ----
    f32x4 wacc0[3], wacc1[3], pacc0[3], pacc1[3];
    {
      const bf16x8 r0h = *(const bf16x8*)&rbfh[p][l15][q4 * 8];
      const bf16x8 r0l = *(const bf16x8*)&rbfl[p][l15][q4 * 8];
      const bf16x8 r1h = *(const bf16x8*)&rbfh[p][16 + l15][q4 * 8];
      const bf16x8 r1l = *(const bf16x8*)&rbfl[p][16 + l15][q4 * 8];
#pragma unroll
      for (int fci = 0; fci < 3; ++fci) {
        f32x4 a0 = __builtin_amdgcn_mfma_f32_16x16x32_bf16(r0h, wrfh[fci], zero4, 0, 0, 0);
        f32x4 a1 = __builtin_amdgcn_mfma_f32_16x16x32_bf16(r1h, wrfh[fci], zero4, 0, 0, 0);
        a0 = __builtin_amdgcn_mfma_f32_16x16x32_bf16(r0l, wrfh[fci], a0, 0, 0, 0);
        a1 = __builtin_amdgcn_mfma_f32_16x16x32_bf16(r1l, wrfh[fci], a1, 0, 0, 0);
        a0 = __builtin_amdgcn_mfma_f32_16x16x32_bf16(r0h, wrfl[fci], a0, 0, 0, 0);
        a1 = __builtin_amdgcn_mfma_f32_16x16x32_bf16(r1h, wrfl[fci], a1, 0, 0, 0);
        wacc0[fci] = a0; wacc1[fci] = a1;
        pacc0[fci] = zero4; pacc1[fci] = zero4;
      }
    }
    // ---- GEMM2: phi = h@W2 (split, 72 MFMA, 6 independent chains) ----
#pragma unroll
    for (int ks = 0; ks < 4; ++ks) {
      const bf16x8 a0h = *(const bf16x8*)&hAh[l15][ks * 32 + q4 * 8];
      const bf16x8 a0l = *(const bf16x8*)&hAl[l15][ks * 32 + q4 * 8];
      const bf16x8 a1h = *(const bf16x8*)&hAh[16 + l15][ks * 32 + q4 * 8];
      const bf16x8 a1l = *(const bf16x8*)&hAl[16 + l15][ks * 32 + q4 * 8];
#pragma unroll
      for (int fci = 0; fci < 3; ++fci) {
        pacc0[fci] = __builtin_amdgcn_mfma_f32_16x16x32_bf16(a0h, w2fh[fci][ks], pacc0[fci], 0, 0, 0);
        pacc1[fci] = __builtin_amdgcn_mfma_f32_16x16x32_bf16(a1h, w2fh[fci][ks], pacc1[fci], 0, 0, 0);
        pacc0[fci] = __builtin_amdgcn_mfma_f32_16x16x32_bf16(a0l, w2fh[fci][ks], pacc0[fci], 0, 0, 0);
        pacc1[fci] = __builtin_amdgcn_mfma_f32_16x16x32_bf16(a1l, w2fh[fci][ks], pacc1[fci], 0, 0, 0);
        pacc0[fci] = __builtin_amdgcn_mfma_f32_16x16x32_bf16(a0h, w2fl[fci][ks], pacc0[fci], 0, 0, 0);
        pacc1[fci] = __builtin_amdgcn_mfma_f32_16x16x32_bf16(a1h, w2fl[fci][ks], pacc1[fci], 0, 0, 0);
      }
    }

    // ---- epilogue: both row-halves, all three categories per wave ----
#pragma unroll
    for (int rr = 0; rr < 4; ++rr) {
      {
        const float4 u4 = urA[p][q4 * 4 + rr];
        const float sp0 = u4.w * (wacc0[0][rr] + brv[0]) * (pacc0[0][rr] + b2v[0]);
        const float sp1 = u4.w * (wacc0[1][rr] + brv[1]) * (pacc0[1][rr] + b2v[1]);
        const float sp2 = u4.w * (wacc0[2][rr] + brv[2]) * (pacc0[2][rr] + b2v[2]);
        accV1[0] += sp0 * vp0[rr][0];
        accV1[1] += sp0 * vp0[rr][1];
        accV1[2] += sp0 * vp0[rr][2];
        accS += sp1;
        accV2[0] += sp2 * u4.x;
        accV2[1] += sp2 * u4.y;
        accV2[2] += sp2 * u4.z;
      }
      {
        const float4 u4 = urA[p][16 + q4 * 4 + rr];
        const float sp0 = u4.w * (wacc1[0][rr] + brv[0]) * (pacc1[0][rr] + b2v[0]);
        const float sp1 = u4.w * (wacc1[1][rr] + brv[1]) * (pacc1[1][rr] + b2v[1]);
        const float sp2 = u4.w * (wacc1[2][rr] + brv[2]) * (pacc1[2][rr] + b2v[2]);
        accV1[0] += sp0 * vp1[rr][0];
        accV1[1] += sp0 * vp1[rr][1];
        accV1[2] += sp0 * vp1[rr][2];
        accS += sp1;
        accV2[0] += sp2 * u4.x;
        accV2[1] += sp2 * u4.y;
        accV2[2] += sp2 * u4.z;
      }
    }
    // urA/rbf double-buffered; sA/hA hazards covered by sync1/sync2 of
    // adjacent iterations (RAW/WAR audited).
  }

  // ---- cross-lane reduce (sum q4 groups) + per-block partials ----
  float* pb = partials + (size_t)blockIdx.x * PART_STRIDE;
#pragma unroll
  for (int c = 0; c < 3; ++c) {
    float tv = accV1[c];
    tv += __shfl_xor(tv, 16);
    tv += __shfl_xor(tv, 32);
    if (ln < 16) pb[c * 128 + jcol] = tv;
  }
  {
    float tv = accS;
    tv += __shfl_xor(tv, 16);
    tv += __shfl_xor(tv, 32);
    if (ln < 16) pb[768 + jcol] = tv;
  }
#pragma unroll
  for (int c = 0; c < 3; ++c) {
    float tv = accV2[c];
    tv += __shfl_xor(tv, 16);
    tv += __shfl_xor(tv, 32);
    if (ln < 16) pb[384 + c * 128 + jcol] = tv;
  }
}

// --- kernel 3: reduce partials -> d_out. out[0:384]=out_v (3x128), [384:512]=out_s
__global__ void reduce_kernel(const float* __restrict__ partials, float* __restrict__ out) {
  const int o = blockIdx.x * 256 + threadIdx.x;   // 0..511
  float a0 = 0.f, a1 = 0.f, a2 = 0.f, a3 = 0.f;
  if (o < 384) {
#pragma unroll 4
    for (int b = 0; b < NBLK; b += 4) {
      a0 += partials[(size_t)(b + 0) * PART_STRIDE + o] + partials[(size_t)(b + 0) * PART_STRIDE + 384 + o];
      a1 += partials[(size_t)(b + 1) * PART_STRIDE + o] + partials[(size_t)(b + 1) * PART_STRIDE + 384 + o];
      a2 += partials[(size_t)(b + 2) * PART_STRIDE + o] + partials[(size_t)(b + 2) * PART_STRIDE + 384 + o];
      a3 += partials[(size_t)(b + 3) * PART_STRIDE + o] + partials[(size_t)(b + 3) * PART_STRIDE + 384 + o];
    }
    out[o] = (a0 + a1) + (a2 + a3);
  } else {
    const int j = o - 384;
#pragma unroll 4
    for (int b = 0; b < NBLK; b += 4) {
      a0 += partials[(size_t)(b + 0) * PART_STRIDE + 768 + j];
      a1 += partials[(size_t)(b + 1) * PART_STRIDE + 768 + j];
      a2 += partials[(size_t)(b + 2) * PART_STRIDE + 768 + j];
      a3 += partials[(size_t)(b + 3) * PART_STRIDE + 768 + j];
    }
    out[o] = (a0 + a1) + (a2 + a3);
  }
}

extern "C" void kernel_launch(void* const* d_in, const int* in_sizes, int n_in,
                              void* d_out, int out_size, void* d_ws, size_t ws_size,
                              hipStream_t stream) {
  const float* s  = (const float*)d_in[0];
  const float* r  = (const float*)d_in[1];
  const float* v  = (const float*)d_in[2];
  const float* W1 = (const float*)d_in[3];
  const float* b1 = (const float*)d_in[4];
  const float* W2 = (const float*)d_in[5];
  const float* b2 = (const float*)d_in[6];
  const float* Wr = (const float*)d_in[7];
  const float* br = (const float*)d_in[8];
  float* out = (float*)d_out;

  // ws: [partials 512*896 f32 = 1835008B][w1t hi+lo 65536B][w2t hi+lo 196608B][wrt hi+lo 49152B]
  char* ws = (char*)d_ws;
  float* partials = (float*)ws;
  unsigned short* w1t = (unsigned short*)(ws + (size_t)NBLK * PART_STRIDE * 4);
  unsigned short* w2t = w1t + 32768;
  unsigned short* wrt = w2t + 98304;

  prep_kernel<<<304, 256, 0, stream>>>(W1, W2, Wr, w1t, w2t, wrt);
  painn_main<<<NBLK, 512, 0, stream>>>(s, r, v, b1, b2, br, w1t, w2t, wrt, partials);
  reduce_kernel<<<2, 256, 0, stream>>>(partials, out);
}